// Round 2
// baseline (1444.041 us; speedup 1.0000x reference)
//
#include <hip/hip_runtime.h>
#include <hip/hip_bf16.h>

// NeRF surrogate renderer, MI355X.
// Layout: 4 consecutive threads per ray (each owns T/4 samples), 256-thr blocks
// -> 64 rays/block. Weights packed in LDS as 32 structs of 16 floats; inner
// loop reads them as float4 broadcasts (uniform address -> conflict-free).
// Output dtype: float32 (reference returns f32; harness maps f32 -> float*).

__device__ __forceinline__ float fast_rcp(float x) {
    return __builtin_amdgcn_rcpf(x); // v_rcp_f32, ~1 ulp, plenty for 2% tol
}

__device__ __forceinline__ float softplus_f(float x) {
    // log1p(exp(x)) stable: max(x,0) + log(1 + exp(-|x|))
    float e = __expf(-fabsf(x));
    return fmaxf(x, 0.0f) + __logf(1.0f + e);
}

__device__ __forceinline__ float sigmoid_f(float x) {
    return fast_rcp(1.0f + __expf(-x));
}

__global__ __launch_bounds__(256)
void nerf_render_kernel(const float* __restrict__ rays_o,
                        const float* __restrict__ rays_d,
                        const float* __restrict__ W1,
                        const float* __restrict__ b1,
                        const float* __restrict__ Wsig,
                        const float* __restrict__ Wsig_d,
                        const float* __restrict__ Wc1,
                        const float* __restrict__ bc1,
                        const float* __restrict__ Wc2,
                        const float* __restrict__ Wc2_d,
                        const int*   __restrict__ num_steps,
                        float* __restrict__ out,
                        int N)
{
    __shared__ __align__(16) float wgt[32 * 16];
    __shared__ __align__(16) float dcw[32 * 4];

    const int tid = threadIdx.x;
    if (tid < 32) {
        const int j = tid;
        wgt[j*16 + 0]  = W1[j];        // W1[0][j]
        wgt[j*16 + 1]  = W1[32 + j];   // W1[1][j]
        wgt[j*16 + 2]  = W1[64 + j];   // W1[2][j]
        wgt[j*16 + 3]  = b1[j];
        wgt[j*16 + 4]  = Wsig[j];
        wgt[j*16 + 5]  = Wsig_d[j];
        wgt[j*16 + 6]  = Wc1[j];       // Wc1[0][j] (x)
        wgt[j*16 + 7]  = Wc1[32 + j];  // Wc1[1][j] (y)
        wgt[j*16 + 8]  = Wc1[64 + j];  // Wc1[2][j] (z)
        wgt[j*16 + 9]  = Wc2[j*3 + 0];
        wgt[j*16 + 10] = Wc2[j*3 + 1];
        wgt[j*16 + 11] = Wc2[j*3 + 2];
        wgt[j*16 + 12] = Wc2_d[j*3 + 0];
        wgt[j*16 + 13] = Wc2_d[j*3 + 1];
        wgt[j*16 + 14] = Wc2_d[j*3 + 2];
        wgt[j*16 + 15] = 0.0f;
        dcw[j*4 + 0] = Wc1[96 + j];    // Wc1[3][j] (dir x)
        dcw[j*4 + 1] = Wc1[128 + j];   // Wc1[4][j] (dir y)
        dcw[j*4 + 2] = Wc1[160 + j];   // Wc1[5][j] (dir z)
        dcw[j*4 + 3] = bc1[j];
    }
    __syncthreads();

    const int ray = blockIdx.x * 64 + (tid >> 2);
    if (ray >= N) return;
    const int seg = tid & 3;
    const int T = num_steps[0];

    const float ox = rays_o[ray*3 + 0], oy = rays_o[ray*3 + 1], oz = rays_o[ray*3 + 2];
    const float rdx = rays_d[ray*3 + 0], rdy = rays_d[ray*3 + 1], rdz = rays_d[ray*3 + 2];
    const float rn = rsqrtf(rdx*rdx + rdy*rdy + rdz*rdz);
    const float dx = rdx * rn, dy = rdy * rn, dz = rdz * rn;

    // AABB slab test, box = [-1,1]^3
    const float ix = 1.0f / dx, iy = 1.0f / dy, iz = 1.0f / dz;
    const float t1x = (-1.0f - ox) * ix, t2x = (1.0f - ox) * ix;
    const float t1y = (-1.0f - oy) * iy, t2y = (1.0f - oy) * iy;
    const float t1z = (-1.0f - oz) * iz, t2z = (1.0f - oz) * iz;
    float nearv = fmaxf(fmaxf(fminf(t1x, t2x), fminf(t1y, t2y)), fminf(t1z, t2z));
    float farv  = fminf(fminf(fmaxf(t1x, t2x), fmaxf(t1y, t2y)), fmaxf(t1z, t2z));
    nearv = fmaxf(nearv, 0.2f);
    farv  = fmaxf(farv, nearv + 1e-6f);

    const float span     = farv - nearv;
    const float stepz    = (T > 1) ? span / (float)(T - 1) : 0.0f;
    const float inv_tm1  = (T > 1) ? 1.0f / (float)(T - 1) : 0.0f;
    const float last_dt  = span / (float)T;

    // dir-dependent part of color-MLP preactivation, per hidden unit
    float dc[32];
    const float4* dcw4 = (const float4*)dcw;
#pragma unroll
    for (int j = 0; j < 32; ++j) {
        const float4 q = dcw4[j];
        dc[j] = fmaf(dx, q.x, fmaf(dy, q.y, fmaf(dz, q.z, q.w)));
    }

    const int Sper = (T + 3) >> 2;
    const int s0 = seg * Sper;
    int cnt = T - s0;
    cnt = (cnt < 0) ? 0 : ((cnt > Sper) ? Sper : cnt);

    // composite state, heads A (main) and D (dummy)
    float iA0 = 0.f, iA1 = 0.f, iA2 = 0.f, dA = 0.f, wsA = 0.f, TA = 1.0f;
    float iD0 = 0.f, iD1 = 0.f, iD2 = 0.f, dD = 0.f, wsD = 0.f, TD = 1.0f;

    const float4* wgt4 = (const float4*)wgt;

    for (int cs = 0; cs < cnt; cs += 4) {
        float xs[4], ys[4], zs[4];
        float sA[4]  = {0,0,0,0}, sD[4]  = {0,0,0,0};
        float r0A[4] = {0,0,0,0}, r1A[4] = {0,0,0,0}, r2A[4] = {0,0,0,0};
        float r0D[4] = {0,0,0,0}, r1D[4] = {0,0,0,0}, r2D[4] = {0,0,0,0};

#pragma unroll
        for (int i = 0; i < 4; ++i) {
            const int t = s0 + cs + i;
            const float zv = fmaf(stepz, (float)t, nearv);
            xs[i] = fminf(fmaxf(fmaf(dx, zv, ox), -1.0f), 1.0f);
            ys[i] = fminf(fmaxf(fmaf(dy, zv, oy), -1.0f), 1.0f);
            zs[i] = fminf(fmaxf(fmaf(dz, zv, oz), -1.0f), 1.0f);
        }

#pragma unroll
        for (int j = 0; j < 32; ++j) {
            const float4 w0 = wgt4[j*4 + 0];
            const float4 w1 = wgt4[j*4 + 1];
            const float4 w2 = wgt4[j*4 + 2];
            const float4 w3 = wgt4[j*4 + 3];
            const float dcj = dc[j];
#pragma unroll
            for (int i = 0; i < 4; ++i) {
                float h = fmaf(xs[i], w0.x, fmaf(ys[i], w0.y, fmaf(zs[i], w0.z, w0.w)));
                h = fmaxf(h, 0.0f);
                sA[i] = fmaf(h, w1.x, sA[i]);
                sD[i] = fmaf(h, w1.y, sD[i]);
                float hc = fmaf(xs[i], w1.z, fmaf(ys[i], w1.w, fmaf(zs[i], w2.x, dcj)));
                hc = fmaxf(hc, 0.0f);
                r0A[i] = fmaf(hc, w2.y, r0A[i]);
                r1A[i] = fmaf(hc, w2.z, r1A[i]);
                r2A[i] = fmaf(hc, w2.w, r2A[i]);
                r0D[i] = fmaf(hc, w3.x, r0D[i]);
                r1D[i] = fmaf(hc, w3.y, r1D[i]);
                r2D[i] = fmaf(hc, w3.z, r2D[i]);
            }
        }

#pragma unroll
        for (int i = 0; i < 4; ++i) {
            const int li = cs + i;
            if (li < cnt) {
                const int t = s0 + li;
                const float sigA = softplus_f(sA[i]);
                const float sigD = softplus_f(sD[i]);
                const float delta = (t < T - 1) ? stepz : last_dt;
                const float z01 = fminf(fmaxf((float)t * inv_tm1, 0.0f), 1.0f);

                const float aA = 1.0f - __expf(-delta * sigA);
                const float wA = aA * TA;
                TA = TA * (1.0f - aA + 1e-15f);
                iA0 = fmaf(wA, sigmoid_f(r0A[i]), iA0);
                iA1 = fmaf(wA, sigmoid_f(r1A[i]), iA1);
                iA2 = fmaf(wA, sigmoid_f(r2A[i]), iA2);
                dA  = fmaf(wA, z01, dA);
                wsA += wA;

                const float aD = 1.0f - __expf(-delta * sigD);
                const float wD = aD * TD;
                TD = TD * (1.0f - aD + 1e-15f);
                iD0 = fmaf(wD, sigmoid_f(r0D[i]), iD0);
                iD1 = fmaf(wD, sigmoid_f(r1D[i]), iD1);
                iD2 = fmaf(wD, sigmoid_f(r2D[i]), iD2);
                dD  = fmaf(wD, z01, dD);
                wsD += wD;
            }
        }
    }

    // combine 4 segments of the ray: out = seg0 + T0*seg1 + T0*T1*seg2 + ...
    // shuffle from pristine copies (lanes also update their own accumulators)
    const float pA0 = iA0, pA1 = iA1, pA2 = iA2, pA3 = dA, pA4 = wsA, pTA = TA;
    const float pD0 = iD0, pD1 = iD1, pD2 = iD2, pD3 = dD, pD4 = wsD, pTD = TD;
    float tA = TA, tD = TD;
#pragma unroll
    for (int u = 1; u < 4; ++u) {
        const float gA0 = __shfl_down(pA0, u, 4);
        const float gA1 = __shfl_down(pA1, u, 4);
        const float gA2 = __shfl_down(pA2, u, 4);
        const float gA3 = __shfl_down(pA3, u, 4);
        const float gA4 = __shfl_down(pA4, u, 4);
        const float gTA = __shfl_down(pTA, u, 4);
        const float gD0 = __shfl_down(pD0, u, 4);
        const float gD1 = __shfl_down(pD1, u, 4);
        const float gD2 = __shfl_down(pD2, u, 4);
        const float gD3 = __shfl_down(pD3, u, 4);
        const float gD4 = __shfl_down(pD4, u, 4);
        const float gTD = __shfl_down(pTD, u, 4);
        iA0 = fmaf(tA, gA0, iA0); iA1 = fmaf(tA, gA1, iA1); iA2 = fmaf(tA, gA2, iA2);
        dA  = fmaf(tA, gA3, dA);  wsA = fmaf(tA, gA4, wsA);
        iD0 = fmaf(tD, gD0, iD0); iD1 = fmaf(tD, gD1, iD1); iD2 = fmaf(tD, gD2, iD2);
        dD  = fmaf(tD, gD3, dD);  wsD = fmaf(tD, gD4, wsD);
        tA *= gTA; tD *= gTD;
    }

    if (seg == 0) {
        const float bgA = 1.0f - wsA;   // bg_color = 1
        const float bgD = 1.0f - wsD;
        float* o = out + (size_t)ray * 9;
        o[0] = iA0 + bgA;
        o[1] = iA1 + bgA;
        o[2] = iA2 + bgA;
        o[3] = dA;
        o[4] = wsA;
        o[5] = iD0 + bgD;
        o[6] = iD1 + bgD;
        o[7] = iD2 + bgD;
        o[8] = dD;
    }
}

extern "C" void kernel_launch(void* const* d_in, const int* in_sizes, int n_in,
                              void* d_out, int out_size, void* d_ws, size_t ws_size,
                              hipStream_t stream) {
    const float* rays_o = (const float*)d_in[0];
    const float* rays_d = (const float*)d_in[1];
    const float* W1     = (const float*)d_in[2];
    const float* b1     = (const float*)d_in[3];
    const float* Wsig   = (const float*)d_in[4];
    const float* Wsig_d = (const float*)d_in[5];
    const float* Wc1    = (const float*)d_in[6];
    const float* bc1    = (const float*)d_in[7];
    const float* Wc2    = (const float*)d_in[8];
    const float* Wc2_d  = (const float*)d_in[9];
    const int* num_steps = (const int*)d_in[10];

    const int N = in_sizes[0] / 3;
    float* out = (float*)d_out;

    const int blocks = (N + 63) / 64;
    hipLaunchKernelGGL(nerf_render_kernel, dim3(blocks), dim3(256), 0, stream,
                       rays_o, rays_d, W1, b1, Wsig, Wsig_d, Wc1, bc1, Wc2, Wc2_d,
                       num_steps, out, N);
}

// Round 3
// 65.367 us; speedup vs baseline: 22.0913x; 22.0913x over previous
//
#include <hip/hip_runtime.h>
#include <hip/hip_bf16.h>

// NeRF surrogate renderer, MI355X — round 3.
// 8 consecutive threads per ray (16 samples each), 256-thr blocks -> 32 rays/block.
// Weights in LDS as 32x float4x4 broadcast structs; per-ray dir-preactivation
// dc[j] in LDS (stride 33 -> conflict-free). j-loop unroll 4 to bound VGPR
// pressure (round-2 spilled: 2.6 GB scratch reads, VALUBusy 6.8%).

__device__ __forceinline__ float fast_rcp(float x) {
    return __builtin_amdgcn_rcpf(x);
}

__device__ __forceinline__ float softplus_f(float x) {
    float e = __expf(-fabsf(x));
    return fmaxf(x, 0.0f) + __logf(1.0f + e);
}

__device__ __forceinline__ float sigmoid_f(float x) {
    return fast_rcp(1.0f + __expf(-x));
}

__global__ __launch_bounds__(256, 4)
void nerf_render_kernel(const float* __restrict__ rays_o,
                        const float* __restrict__ rays_d,
                        const float* __restrict__ W1,
                        const float* __restrict__ b1,
                        const float* __restrict__ Wsig,
                        const float* __restrict__ Wsig_d,
                        const float* __restrict__ Wc1,
                        const float* __restrict__ bc1,
                        const float* __restrict__ Wc2,
                        const float* __restrict__ Wc2_d,
                        const int*   __restrict__ num_steps,
                        float* __restrict__ out,
                        int N)
{
    __shared__ __align__(16) float wgt[32 * 16];
    __shared__ float dc_lds[32 * 33];   // [rayLocal][j], stride 33 -> conflict-free

    const int tid = threadIdx.x;
    if (tid < 32) {
        const int j = tid;
        wgt[j*16 + 0]  = W1[j];
        wgt[j*16 + 1]  = W1[32 + j];
        wgt[j*16 + 2]  = W1[64 + j];
        wgt[j*16 + 3]  = b1[j];
        wgt[j*16 + 4]  = Wsig[j];
        wgt[j*16 + 5]  = Wsig_d[j];
        wgt[j*16 + 6]  = Wc1[j];
        wgt[j*16 + 7]  = Wc1[32 + j];
        wgt[j*16 + 8]  = Wc1[64 + j];
        wgt[j*16 + 9]  = Wc2[j*3 + 0];
        wgt[j*16 + 10] = Wc2[j*3 + 1];
        wgt[j*16 + 11] = Wc2[j*3 + 2];
        wgt[j*16 + 12] = Wc2_d[j*3 + 0];
        wgt[j*16 + 13] = Wc2_d[j*3 + 1];
        wgt[j*16 + 14] = Wc2_d[j*3 + 2];
        wgt[j*16 + 15] = 0.0f;
    }

    const int rayL = tid >> 3;
    const int seg  = tid & 7;
    const int ray  = blockIdx.x * 32 + rayL;
    const int rayc = (ray < N) ? ray : (N - 1);   // clamp so all threads reach barrier
    const int T = num_steps[0];

    const float ox = rays_o[rayc*3 + 0], oy = rays_o[rayc*3 + 1], oz = rays_o[rayc*3 + 2];
    const float rdx = rays_d[rayc*3 + 0], rdy = rays_d[rayc*3 + 1], rdz = rays_d[rayc*3 + 2];
    const float rn = rsqrtf(rdx*rdx + rdy*rdy + rdz*rdz);
    const float dx = rdx * rn, dy = rdy * rn, dz = rdz * rn;

    // per-ray dir-dependent color preactivation: dc[j] = d . Wc1[3:6,j] + bc1[j]
    // each of the ray's 8 threads computes 4 of the 32 units, from global (L1-hot)
#pragma unroll
    for (int jj = 0; jj < 4; ++jj) {
        const int j = seg * 4 + jj;
        const float q0 = Wc1[96 + j], q1 = Wc1[128 + j], q2 = Wc1[160 + j], qb = bc1[j];
        dc_lds[rayL*33 + j] = fmaf(dx, q0, fmaf(dy, q1, fmaf(dz, q2, qb)));
    }
    __syncthreads();
    if (ray >= N) return;

    // AABB slab test, box = [-1,1]^3
    const float ix = 1.0f / dx, iy = 1.0f / dy, iz = 1.0f / dz;
    const float t1x = (-1.0f - ox) * ix, t2x = (1.0f - ox) * ix;
    const float t1y = (-1.0f - oy) * iy, t2y = (1.0f - oy) * iy;
    const float t1z = (-1.0f - oz) * iz, t2z = (1.0f - oz) * iz;
    float nearv = fmaxf(fmaxf(fminf(t1x, t2x), fminf(t1y, t2y)), fminf(t1z, t2z));
    float farv  = fminf(fminf(fmaxf(t1x, t2x), fmaxf(t1y, t2y)), fmaxf(t1z, t2z));
    nearv = fmaxf(nearv, 0.2f);
    farv  = fmaxf(farv, nearv + 1e-6f);

    const float span    = farv - nearv;
    const float stepz   = (T > 1) ? span / (float)(T - 1) : 0.0f;
    const float inv_tm1 = (T > 1) ? 1.0f / (float)(T - 1) : 0.0f;
    const float last_dt = span / (float)T;

    const int Sper = (T + 7) >> 3;
    const int s0 = seg * Sper;
    int cnt = T - s0;
    cnt = (cnt < 0) ? 0 : ((cnt > Sper) ? Sper : cnt);

    float iA0 = 0.f, iA1 = 0.f, iA2 = 0.f, dA = 0.f, wsA = 0.f, TAx = 1.0f;
    float iD0 = 0.f, iD1 = 0.f, iD2 = 0.f, dD = 0.f, wsD = 0.f, TDx = 1.0f;

    const float4* wgt4 = (const float4*)wgt;
    const float*  dcp  = dc_lds + rayL*33;

    for (int cs = 0; cs < cnt; cs += 4) {
        float xs[4], ys[4], zs[4];
        float sA[4]  = {0,0,0,0}, sD[4]  = {0,0,0,0};
        float r0A[4] = {0,0,0,0}, r1A[4] = {0,0,0,0}, r2A[4] = {0,0,0,0};
        float r0D[4] = {0,0,0,0}, r1D[4] = {0,0,0,0}, r2D[4] = {0,0,0,0};

#pragma unroll
        for (int i = 0; i < 4; ++i) {
            const int t = s0 + cs + i;
            const float zv = fmaf(stepz, (float)t, nearv);
            xs[i] = fminf(fmaxf(fmaf(dx, zv, ox), -1.0f), 1.0f);
            ys[i] = fminf(fmaxf(fmaf(dy, zv, oy), -1.0f), 1.0f);
            zs[i] = fminf(fmaxf(fmaf(dz, zv, oz), -1.0f), 1.0f);
        }

#pragma unroll 4
        for (int j = 0; j < 32; ++j) {
            const float4 w0 = wgt4[j*4 + 0];
            const float4 w1 = wgt4[j*4 + 1];
            const float4 w2 = wgt4[j*4 + 2];
            const float4 w3 = wgt4[j*4 + 3];
            const float dcj = dcp[j];
#pragma unroll
            for (int i = 0; i < 4; ++i) {
                float h = fmaf(xs[i], w0.x, fmaf(ys[i], w0.y, fmaf(zs[i], w0.z, w0.w)));
                h = fmaxf(h, 0.0f);
                sA[i] = fmaf(h, w1.x, sA[i]);
                sD[i] = fmaf(h, w1.y, sD[i]);
                float hc = fmaf(xs[i], w1.z, fmaf(ys[i], w1.w, fmaf(zs[i], w2.x, dcj)));
                hc = fmaxf(hc, 0.0f);
                r0A[i] = fmaf(hc, w2.y, r0A[i]);
                r1A[i] = fmaf(hc, w2.z, r1A[i]);
                r2A[i] = fmaf(hc, w2.w, r2A[i]);
                r0D[i] = fmaf(hc, w3.x, r0D[i]);
                r1D[i] = fmaf(hc, w3.y, r1D[i]);
                r2D[i] = fmaf(hc, w3.z, r2D[i]);
            }
        }

#pragma unroll
        for (int i = 0; i < 4; ++i) {
            const int li = cs + i;
            if (li < cnt) {
                const int t = s0 + li;
                const float sigA = softplus_f(sA[i]);
                const float sigD = softplus_f(sD[i]);
                const float delta = (t < T - 1) ? stepz : last_dt;
                const float z01 = fminf(fmaxf((float)t * inv_tm1, 0.0f), 1.0f);

                const float aA = 1.0f - __expf(-delta * sigA);
                const float wA = aA * TAx;
                TAx = TAx * (1.0f - aA + 1e-15f);
                iA0 = fmaf(wA, sigmoid_f(r0A[i]), iA0);
                iA1 = fmaf(wA, sigmoid_f(r1A[i]), iA1);
                iA2 = fmaf(wA, sigmoid_f(r2A[i]), iA2);
                dA  = fmaf(wA, z01, dA);
                wsA += wA;

                const float aD = 1.0f - __expf(-delta * sigD);
                const float wD = aD * TDx;
                TDx = TDx * (1.0f - aD + 1e-15f);
                iD0 = fmaf(wD, sigmoid_f(r0D[i]), iD0);
                iD1 = fmaf(wD, sigmoid_f(r1D[i]), iD1);
                iD2 = fmaf(wD, sigmoid_f(r2D[i]), iD2);
                dD  = fmaf(wD, z01, dD);
                wsD += wD;
            }
        }
    }

    // combine the ray's 8 segments: prefix-transmittance over seg order
    const float pA0 = iA0, pA1 = iA1, pA2 = iA2, pA3 = dA, pA4 = wsA, pTA = TAx;
    const float pD0 = iD0, pD1 = iD1, pD2 = iD2, pD3 = dD, pD4 = wsD, pTD = TDx;
    float tA = TAx, tD = TDx;
#pragma unroll
    for (int u = 1; u < 8; ++u) {
        const float gA0 = __shfl_down(pA0, u, 8);
        const float gA1 = __shfl_down(pA1, u, 8);
        const float gA2 = __shfl_down(pA2, u, 8);
        const float gA3 = __shfl_down(pA3, u, 8);
        const float gA4 = __shfl_down(pA4, u, 8);
        const float gTA = __shfl_down(pTA, u, 8);
        const float gD0 = __shfl_down(pD0, u, 8);
        const float gD1 = __shfl_down(pD1, u, 8);
        const float gD2 = __shfl_down(pD2, u, 8);
        const float gD3 = __shfl_down(pD3, u, 8);
        const float gD4 = __shfl_down(pD4, u, 8);
        const float gTD = __shfl_down(pTD, u, 8);
        iA0 = fmaf(tA, gA0, iA0); iA1 = fmaf(tA, gA1, iA1); iA2 = fmaf(tA, gA2, iA2);
        dA  = fmaf(tA, gA3, dA);  wsA = fmaf(tA, gA4, wsA);
        iD0 = fmaf(tD, gD0, iD0); iD1 = fmaf(tD, gD1, iD1); iD2 = fmaf(tD, gD2, iD2);
        dD  = fmaf(tD, gD3, dD);  wsD = fmaf(tD, gD4, wsD);
        tA *= gTA; tD *= gTD;
    }

    if (seg == 0) {
        const float bgA = 1.0f - wsA;
        const float bgD = 1.0f - wsD;
        float* o = out + (size_t)ray * 9;
        o[0] = iA0 + bgA;
        o[1] = iA1 + bgA;
        o[2] = iA2 + bgA;
        o[3] = dA;
        o[4] = wsA;
        o[5] = iD0 + bgD;
        o[6] = iD1 + bgD;
        o[7] = iD2 + bgD;
        o[8] = dD;
    }
}

extern "C" void kernel_launch(void* const* d_in, const int* in_sizes, int n_in,
                              void* d_out, int out_size, void* d_ws, size_t ws_size,
                              hipStream_t stream) {
    const float* rays_o = (const float*)d_in[0];
    const float* rays_d = (const float*)d_in[1];
    const float* W1     = (const float*)d_in[2];
    const float* b1     = (const float*)d_in[3];
    const float* Wsig   = (const float*)d_in[4];
    const float* Wsig_d = (const float*)d_in[5];
    const float* Wc1    = (const float*)d_in[6];
    const float* bc1    = (const float*)d_in[7];
    const float* Wc2    = (const float*)d_in[8];
    const float* Wc2_d  = (const float*)d_in[9];
    const int* num_steps = (const int*)d_in[10];

    const int N = in_sizes[0] / 3;
    float* out = (float*)d_out;

    const int blocks = (N + 31) / 32;   // 32 rays per 256-thread block
    hipLaunchKernelGGL(nerf_render_kernel, dim3(blocks), dim3(256), 0, stream,
                       rays_o, rays_d, W1, b1, Wsig, Wsig_d, Wc1, bc1, Wc2, Wc2_d,
                       num_steps, out, N);
}

// Round 4
// 65.251 us; speedup vs baseline: 22.1306x; 1.0018x over previous
//
#include <hip/hip_runtime.h>
#include <hip/hip_bf16.h>

// NeRF surrogate renderer, MI355X — round 4: packed-fp32 (v_pk_fma_f32) inner loop.
// 8 threads/ray (16 samples each), 256-thr blocks -> 32 rays/block.
// Weights in LDS pre-DUPLICATED as float4=(a,a,b,b) so packed FMAs get (w,w)
// broadcast operands straight from ds_read_b128. Samples processed in pairs.

typedef float v2f __attribute__((ext_vector_type(2)));
typedef float v4f __attribute__((ext_vector_type(4)));

__device__ __forceinline__ float fast_rcp(float x) { return __builtin_amdgcn_rcpf(x); }

__device__ __forceinline__ float softplus_f(float x) {
    float e = __expf(-fabsf(x));
    return fmaxf(x, 0.0f) + __logf(1.0f + e);
}
__device__ __forceinline__ float sigmoid_f(float x) {
    return fast_rcp(1.0f + __expf(-x));
}

__device__ __forceinline__ v2f pkfma(v2f a, v2f b, v2f c) {
    return __builtin_elementwise_fma(a, b, c);   // -> v_pk_fma_f32 on gfx950
}
__device__ __forceinline__ v2f relu2(v2f a) {
    const v2f z = {0.0f, 0.0f};
    return __builtin_elementwise_max(a, z);
}
__device__ __forceinline__ v2f clamp11(v2f a) {
    const v2f lo = {-1.0f, -1.0f}, hi = {1.0f, 1.0f};
    return __builtin_elementwise_min(__builtin_elementwise_max(a, lo), hi);
}
#define SHV(q, i, j) __builtin_shufflevector((q), (q), (i), (j))

__global__ __launch_bounds__(256, 4)
void nerf_render_kernel(const float* __restrict__ rays_o,
                        const float* __restrict__ rays_d,
                        const float* __restrict__ W1,
                        const float* __restrict__ b1,
                        const float* __restrict__ Wsig,
                        const float* __restrict__ Wsig_d,
                        const float* __restrict__ Wc1,
                        const float* __restrict__ bc1,
                        const float* __restrict__ Wc2,
                        const float* __restrict__ Wc2_d,
                        const int*   __restrict__ num_steps,
                        float* __restrict__ out,
                        int N)
{
    __shared__ __align__(16) v4f wq[32 * 8];     // per j: 8 quads of duplicated pairs
    __shared__ v2f dc2[32 * 33];                 // per-ray dir preact, duplicated

    const int tid = threadIdx.x;
    if (tid < 32) {
        const int j = tid;
        const float a0 = W1[j],       a1 = W1[32 + j],  a2 = W1[64 + j],  a3 = b1[j];
        const float a4 = Wsig[j],     a5 = Wsig_d[j];
        const float a6 = Wc1[j],      a7 = Wc1[32 + j], a8 = Wc1[64 + j];
        const float a9  = Wc2[j*3+0], a10 = Wc2[j*3+1], a11 = Wc2[j*3+2];
        const float a12 = Wc2_d[j*3+0], a13 = Wc2_d[j*3+1], a14 = Wc2_d[j*3+2];
        wq[j*8 + 0] = (v4f){a0, a0, a1, a1};      // W1x, W1y
        wq[j*8 + 1] = (v4f){a2, a2, a3, a3};      // W1z, b1
        wq[j*8 + 2] = (v4f){a4, a4, a5, a5};      // Wsig, Wsig_d
        wq[j*8 + 3] = (v4f){a6, a6, a7, a7};      // Wc1x, Wc1y
        wq[j*8 + 4] = (v4f){a8, a8, a9, a9};      // Wc1z, Wc2A0
        wq[j*8 + 5] = (v4f){a10, a10, a11, a11};  // Wc2A1, Wc2A2
        wq[j*8 + 6] = (v4f){a12, a12, a13, a13};  // Wc2D0, Wc2D1
        wq[j*8 + 7] = (v4f){a14, a14, 0.f, 0.f};  // Wc2D2, pad
    }

    const int rayL = tid >> 3;
    const int seg  = tid & 7;
    const int ray  = blockIdx.x * 32 + rayL;
    const int rayc = (ray < N) ? ray : (N - 1);
    const int T = num_steps[0];

    const float ox = rays_o[rayc*3 + 0], oy = rays_o[rayc*3 + 1], oz = rays_o[rayc*3 + 2];
    const float rdx = rays_d[rayc*3 + 0], rdy = rays_d[rayc*3 + 1], rdz = rays_d[rayc*3 + 2];
    const float rn = rsqrtf(rdx*rdx + rdy*rdy + rdz*rdz);
    const float dx = rdx * rn, dy = rdy * rn, dz = rdz * rn;

    // per-ray dir-dependent color preactivation, duplicated pairs
#pragma unroll
    for (int jj = 0; jj < 4; ++jj) {
        const int j = seg * 4 + jj;
        const float v = fmaf(dx, Wc1[96 + j], fmaf(dy, Wc1[128 + j], fmaf(dz, Wc1[160 + j], bc1[j])));
        dc2[rayL*33 + j] = (v2f){v, v};
    }
    __syncthreads();
    if (ray >= N) return;

    // AABB slab test, box = [-1,1]^3
    const float ix = 1.0f / dx, iy = 1.0f / dy, iz = 1.0f / dz;
    const float t1x = (-1.0f - ox) * ix, t2x = (1.0f - ox) * ix;
    const float t1y = (-1.0f - oy) * iy, t2y = (1.0f - oy) * iy;
    const float t1z = (-1.0f - oz) * iz, t2z = (1.0f - oz) * iz;
    float nearv = fmaxf(fmaxf(fminf(t1x, t2x), fminf(t1y, t2y)), fminf(t1z, t2z));
    float farv  = fminf(fminf(fmaxf(t1x, t2x), fmaxf(t1y, t2y)), fmaxf(t1z, t2z));
    nearv = fmaxf(nearv, 0.2f);
    farv  = fmaxf(farv, nearv + 1e-6f);

    const float span    = farv - nearv;
    const float stepz   = (T > 1) ? span / (float)(T - 1) : 0.0f;
    const float inv_tm1 = (T > 1) ? 1.0f / (float)(T - 1) : 0.0f;
    const float last_dt = span / (float)T;

    const v2f dxp = {dx, dx}, dyp = {dy, dy}, dzp = {dz, dz};
    const v2f oxp = {ox, ox}, oyp = {oy, oy}, ozp = {oz, oz};

    const int Sper = (T + 7) >> 3;
    const int s0 = seg * Sper;
    int cnt = T - s0;
    cnt = (cnt < 0) ? 0 : ((cnt > Sper) ? Sper : cnt);

    float iA0 = 0.f, iA1 = 0.f, iA2 = 0.f, dAc = 0.f, wsA = 0.f, TAx = 1.0f;
    float iD0 = 0.f, iD1 = 0.f, iD2 = 0.f, dDc = 0.f, wsD = 0.f, TDx = 1.0f;

    for (int cs = 0; cs < cnt; cs += 4) {
        // packed positions: pair0 = samples (cs,cs+1), pair1 = (cs+2,cs+3)
        const float tb = (float)(s0 + cs);
        const v2f zv0 = {fmaf(stepz, tb,        nearv), fmaf(stepz, tb + 1.0f, nearv)};
        const v2f zv1 = {fmaf(stepz, tb + 2.0f, nearv), fmaf(stepz, tb + 3.0f, nearv)};
        const v2f X0 = clamp11(pkfma(dxp, zv0, oxp));
        const v2f Y0 = clamp11(pkfma(dyp, zv0, oyp));
        const v2f Z0 = clamp11(pkfma(dzp, zv0, ozp));
        const v2f X1 = clamp11(pkfma(dxp, zv1, oxp));
        const v2f Y1 = clamp11(pkfma(dyp, zv1, oyp));
        const v2f Z1 = clamp11(pkfma(dzp, zv1, ozp));

        v2f sA0v = {0,0}, sD0v = {0,0}, c0A0 = {0,0}, c1A0 = {0,0}, c2A0 = {0,0},
            c0D0 = {0,0}, c1D0 = {0,0}, c2D0 = {0,0};
        v2f sA1v = {0,0}, sD1v = {0,0}, c0A1 = {0,0}, c1A1 = {0,0}, c2A1 = {0,0},
            c0D1 = {0,0}, c1D1 = {0,0}, c2D1 = {0,0};

#pragma unroll 2
        for (int j = 0; j < 32; ++j) {
            const v4f q0 = wq[j*8 + 0];
            const v4f q1 = wq[j*8 + 1];
            const v4f q2 = wq[j*8 + 2];
            const v4f q3 = wq[j*8 + 3];
            const v4f q4 = wq[j*8 + 4];
            const v4f q5 = wq[j*8 + 5];
            const v4f q6 = wq[j*8 + 6];
            const v4f q7 = wq[j*8 + 7];
            const v2f dcp = dc2[rayL*33 + j];

            const v2f w1x = SHV(q0, 0, 1), w1y = SHV(q0, 2, 3);
            const v2f w1z = SHV(q1, 0, 1), b1p = SHV(q1, 2, 3);
            const v2f wsa = SHV(q2, 0, 1), wsd = SHV(q2, 2, 3);
            const v2f wcx = SHV(q3, 0, 1), wcy = SHV(q3, 2, 3);
            const v2f wcz = SHV(q4, 0, 1), wa0 = SHV(q4, 2, 3);
            const v2f wa1 = SHV(q5, 0, 1), wa2 = SHV(q5, 2, 3);
            const v2f wd0 = SHV(q6, 0, 1), wd1 = SHV(q6, 2, 3);
            const v2f wd2 = SHV(q7, 0, 1);

            v2f h0 = pkfma(X0, w1x, pkfma(Y0, w1y, pkfma(Z0, w1z, b1p)));
            v2f h1 = pkfma(X1, w1x, pkfma(Y1, w1y, pkfma(Z1, w1z, b1p)));
            h0 = relu2(h0); h1 = relu2(h1);
            sA0v = pkfma(h0, wsa, sA0v);  sD0v = pkfma(h0, wsd, sD0v);
            sA1v = pkfma(h1, wsa, sA1v);  sD1v = pkfma(h1, wsd, sD1v);

            v2f g0 = pkfma(X0, wcx, pkfma(Y0, wcy, pkfma(Z0, wcz, dcp)));
            v2f g1 = pkfma(X1, wcx, pkfma(Y1, wcy, pkfma(Z1, wcz, dcp)));
            g0 = relu2(g0); g1 = relu2(g1);
            c0A0 = pkfma(g0, wa0, c0A0);  c1A0 = pkfma(g0, wa1, c1A0);  c2A0 = pkfma(g0, wa2, c2A0);
            c0D0 = pkfma(g0, wd0, c0D0);  c1D0 = pkfma(g0, wd1, c1D0);  c2D0 = pkfma(g0, wd2, c2D0);
            c0A1 = pkfma(g1, wa0, c0A1);  c1A1 = pkfma(g1, wa1, c1A1);  c2A1 = pkfma(g1, wa2, c2A1);
            c0D1 = pkfma(g1, wd0, c0D1);  c1D1 = pkfma(g1, wd1, c1D1);  c2D1 = pkfma(g1, wd2, c2D1);
        }

#define COMPOSITE(I, SA, SD, R0A, R1A, R2A, R0D, R1D, R2D)                         \
        do {                                                                        \
            const int li = cs + (I);                                                \
            if (li < cnt) {                                                         \
                const int t = s0 + li;                                              \
                const float sigA = softplus_f(SA);                                  \
                const float sigD = softplus_f(SD);                                  \
                const float delta = (t < T - 1) ? stepz : last_dt;                  \
                const float z01 = fminf(fmaxf((float)t * inv_tm1, 0.0f), 1.0f);     \
                const float aA = 1.0f - __expf(-delta * sigA);                      \
                const float wA = aA * TAx;                                          \
                TAx = TAx * (1.0f - aA + 1e-15f);                                   \
                iA0 = fmaf(wA, sigmoid_f(R0A), iA0);                                \
                iA1 = fmaf(wA, sigmoid_f(R1A), iA1);                                \
                iA2 = fmaf(wA, sigmoid_f(R2A), iA2);                                \
                dAc = fmaf(wA, z01, dAc);                                           \
                wsA += wA;                                                          \
                const float aD = 1.0f - __expf(-delta * sigD);                      \
                const float wD = aD * TDx;                                          \
                TDx = TDx * (1.0f - aD + 1e-15f);                                   \
                iD0 = fmaf(wD, sigmoid_f(R0D), iD0);                                \
                iD1 = fmaf(wD, sigmoid_f(R1D), iD1);                                \
                iD2 = fmaf(wD, sigmoid_f(R2D), iD2);                                \
                dDc = fmaf(wD, z01, dDc);                                           \
                wsD += wD;                                                          \
            }                                                                       \
        } while (0)

        COMPOSITE(0, sA0v.x, sD0v.x, c0A0.x, c1A0.x, c2A0.x, c0D0.x, c1D0.x, c2D0.x);
        COMPOSITE(1, sA0v.y, sD0v.y, c0A0.y, c1A0.y, c2A0.y, c0D0.y, c1D0.y, c2D0.y);
        COMPOSITE(2, sA1v.x, sD1v.x, c0A1.x, c1A1.x, c2A1.x, c0D1.x, c1D1.x, c2D1.x);
        COMPOSITE(3, sA1v.y, sD1v.y, c0A1.y, c1A1.y, c2A1.y, c0D1.y, c1D1.y, c2D1.y);
#undef COMPOSITE
    }

    // combine the ray's 8 segments: prefix-transmittance over seg order
    const float pA0 = iA0, pA1 = iA1, pA2 = iA2, pA3 = dAc, pA4 = wsA, pTA = TAx;
    const float pD0 = iD0, pD1 = iD1, pD2 = iD2, pD3 = dDc, pD4 = wsD, pTD = TDx;
    float tA = TAx, tD = TDx;
#pragma unroll
    for (int u = 1; u < 8; ++u) {
        const float gA0 = __shfl_down(pA0, u, 8);
        const float gA1 = __shfl_down(pA1, u, 8);
        const float gA2 = __shfl_down(pA2, u, 8);
        const float gA3 = __shfl_down(pA3, u, 8);
        const float gA4 = __shfl_down(pA4, u, 8);
        const float gTA = __shfl_down(pTA, u, 8);
        const float gD0 = __shfl_down(pD0, u, 8);
        const float gD1 = __shfl_down(pD1, u, 8);
        const float gD2 = __shfl_down(pD2, u, 8);
        const float gD3 = __shfl_down(pD3, u, 8);
        const float gD4 = __shfl_down(pD4, u, 8);
        const float gTD = __shfl_down(pTD, u, 8);
        iA0 = fmaf(tA, gA0, iA0); iA1 = fmaf(tA, gA1, iA1); iA2 = fmaf(tA, gA2, iA2);
        dAc = fmaf(tA, gA3, dAc); wsA = fmaf(tA, gA4, wsA);
        iD0 = fmaf(tD, gD0, iD0); iD1 = fmaf(tD, gD1, iD1); iD2 = fmaf(tD, gD2, iD2);
        dDc = fmaf(tD, gD3, dDc); wsD = fmaf(tD, gD4, wsD);
        tA *= gTA; tD *= gTD;
    }

    if (seg == 0) {
        const float bgA = 1.0f - wsA;
        const float bgD = 1.0f - wsD;
        float* o = out + (size_t)ray * 9;
        o[0] = iA0 + bgA;
        o[1] = iA1 + bgA;
        o[2] = iA2 + bgA;
        o[3] = dAc;
        o[4] = wsA;
        o[5] = iD0 + bgD;
        o[6] = iD1 + bgD;
        o[7] = iD2 + bgD;
        o[8] = dDc;
    }
}

extern "C" void kernel_launch(void* const* d_in, const int* in_sizes, int n_in,
                              void* d_out, int out_size, void* d_ws, size_t ws_size,
                              hipStream_t stream) {
    const float* rays_o = (const float*)d_in[0];
    const float* rays_d = (const float*)d_in[1];
    const float* W1     = (const float*)d_in[2];
    const float* b1     = (const float*)d_in[3];
    const float* Wsig   = (const float*)d_in[4];
    const float* Wsig_d = (const float*)d_in[5];
    const float* Wc1    = (const float*)d_in[6];
    const float* bc1    = (const float*)d_in[7];
    const float* Wc2    = (const float*)d_in[8];
    const float* Wc2_d  = (const float*)d_in[9];
    const int* num_steps = (const int*)d_in[10];

    const int N = in_sizes[0] / 3;
    float* out = (float*)d_out;

    const int blocks = (N + 31) / 32;   // 32 rays per 256-thread block
    hipLaunchKernelGGL(nerf_render_kernel, dim3(blocks), dim3(256), 0, stream,
                       rays_o, rays_d, W1, b1, Wsig, Wsig_d, Wc1, bc1, Wc2, Wc2_d,
                       num_steps, out, N);
}

// Round 5
// 64.619 us; speedup vs baseline: 22.3469x; 1.0098x over previous
//
#include <hip/hip_runtime.h>
#include <hip/hip_bf16.h>

// NeRF surrogate renderer, MI355X — round 5.
// Round-4 lesson: LDS-pipe-bound (1152 ds_read/wave). Fix: weights are
// wave-uniform -> prep kernel packs them into d_ws pre-duplicated as (w,w)
// pairs; main kernel reads with uniform index -> s_load into SGPRs (K$ pipe),
// feeding v_pk_fma_f32 as even-aligned SGPR-pair operands. LDS keeps only the
// per-ray dir-preactivation. 16 threads/ray (8192 waves), log-scan combine.

typedef float v2f __attribute__((ext_vector_type(2)));
typedef float v4f __attribute__((ext_vector_type(4)));

__device__ __forceinline__ float fast_rcp(float x) { return __builtin_amdgcn_rcpf(x); }

__device__ __forceinline__ float softplus_f(float x) {
    float e = __expf(-fabsf(x));
    return fmaxf(x, 0.0f) + __logf(1.0f + e);
}
__device__ __forceinline__ float sigmoid_f(float x) {
    return fast_rcp(1.0f + __expf(-x));
}

__device__ __forceinline__ v2f pkfma(v2f a, v2f b, v2f c) {
    return __builtin_elementwise_fma(a, b, c);   // v_pk_fma_f32
}
__device__ __forceinline__ v2f relu2(v2f a) {
    const v2f z = {0.0f, 0.0f};
    return __builtin_elementwise_max(a, z);
}
__device__ __forceinline__ v2f clamp11(v2f a) {
    const v2f lo = {-1.0f, -1.0f}, hi = {1.0f, 1.0f};
    return __builtin_elementwise_min(__builtin_elementwise_max(a, lo), hi);
}
#define SHV(q, i, j) __builtin_shufflevector((q), (q), (i), (j))

// ---- prep: pack weights into d_ws as 32 j-structs of 16 duplicated pairs ----
// pair p of unit j at ws[(j*16+p)*2 .. +1] = (v, v)
__global__ __launch_bounds__(256)
void nerf_prep_kernel(const float* __restrict__ W1, const float* __restrict__ b1,
                      const float* __restrict__ Wsig, const float* __restrict__ Wsig_d,
                      const float* __restrict__ Wc1, const float* __restrict__ Wc2,
                      const float* __restrict__ Wc2_d, float* __restrict__ ws)
{
    int q = threadIdx.x;
#pragma unroll
    for (int k = 0; k < 2; ++k, q += 256) {
        const int j = q >> 4, p = q & 15;
        float v;
        switch (p) {
            case 0:  v = W1[j];        break;
            case 1:  v = W1[32 + j];   break;
            case 2:  v = W1[64 + j];   break;
            case 3:  v = b1[j];        break;
            case 4:  v = Wsig[j];      break;
            case 5:  v = Wsig_d[j];    break;
            case 6:  v = Wc1[j];       break;
            case 7:  v = Wc1[32 + j];  break;
            case 8:  v = Wc1[64 + j];  break;
            case 9:  v = Wc2[j*3 + 0]; break;
            case 10: v = Wc2[j*3 + 1]; break;
            case 11: v = Wc2[j*3 + 2]; break;
            case 12: v = Wc2_d[j*3 + 0]; break;
            case 13: v = Wc2_d[j*3 + 1]; break;
            case 14: v = Wc2_d[j*3 + 2]; break;
            default: v = 0.0f; break;
        }
        ws[q*2 + 0] = v;
        ws[q*2 + 1] = v;
    }
}

// ---- main: 16 threads/ray, 16 rays per 256-thr block ----
__global__ __launch_bounds__(256, 4)
void nerf_render_kernel(const float* __restrict__ rays_o,
                        const float* __restrict__ rays_d,
                        const float* __restrict__ Wc1,
                        const float* __restrict__ bc1,
                        const float* __restrict__ wsm,   // packed weights (d_ws)
                        const int*   __restrict__ num_steps,
                        float* __restrict__ out,
                        int N)
{
    __shared__ v2f dc2[16 * 33];   // [rayLocal][j] duplicated pairs, stride 33

    const int tid  = threadIdx.x;
    const int rayL = tid >> 4;
    const int seg  = tid & 15;
    const int ray  = blockIdx.x * 16 + rayL;
    const int rayc = (ray < N) ? ray : (N - 1);
    const int T = num_steps[0];

    const float ox = rays_o[rayc*3 + 0], oy = rays_o[rayc*3 + 1], oz = rays_o[rayc*3 + 2];
    const float rdx = rays_d[rayc*3 + 0], rdy = rays_d[rayc*3 + 1], rdz = rays_d[rayc*3 + 2];
    const float rn = rsqrtf(rdx*rdx + rdy*rdy + rdz*rdz);
    const float dx = rdx * rn, dy = rdy * rn, dz = rdz * rn;

    // per-ray dir preactivation: each of the 16 threads computes 2 units
#pragma unroll
    for (int jj = 0; jj < 2; ++jj) {
        const int j = seg * 2 + jj;
        const float v = fmaf(dx, Wc1[96 + j], fmaf(dy, Wc1[128 + j], fmaf(dz, Wc1[160 + j], bc1[j])));
        dc2[rayL*33 + j] = (v2f){v, v};
    }
    __syncthreads();
    if (ray >= N) return;

    // AABB slab test, box = [-1,1]^3
    const float ix = 1.0f / dx, iy = 1.0f / dy, iz = 1.0f / dz;
    const float t1x = (-1.0f - ox) * ix, t2x = (1.0f - ox) * ix;
    const float t1y = (-1.0f - oy) * iy, t2y = (1.0f - oy) * iy;
    const float t1z = (-1.0f - oz) * iz, t2z = (1.0f - oz) * iz;
    float nearv = fmaxf(fmaxf(fminf(t1x, t2x), fminf(t1y, t2y)), fminf(t1z, t2z));
    float farv  = fminf(fminf(fmaxf(t1x, t2x), fmaxf(t1y, t2y)), fmaxf(t1z, t2z));
    nearv = fmaxf(nearv, 0.2f);
    farv  = fmaxf(farv, nearv + 1e-6f);

    const float span    = farv - nearv;
    const float stepz   = (T > 1) ? span / (float)(T - 1) : 0.0f;
    const float inv_tm1 = (T > 1) ? 1.0f / (float)(T - 1) : 0.0f;
    const float last_dt = span / (float)T;

    const v2f dxp = {dx, dx}, dyp = {dy, dy}, dzp = {dz, dz};
    const v2f oxp = {ox, ox}, oyp = {oy, oy}, ozp = {oz, oz};

    const int Sper = (T + 15) >> 4;
    const int s0 = seg * Sper;
    int cnt = T - s0;
    cnt = (cnt < 0) ? 0 : ((cnt > Sper) ? Sper : cnt);

    float iA0 = 0.f, iA1 = 0.f, iA2 = 0.f, dAc = 0.f, wsA = 0.f, TAx = 1.0f;
    float iD0 = 0.f, iD1 = 0.f, iD2 = 0.f, dDc = 0.f, wsD = 0.f, TDx = 1.0f;

    const v4f* wv = (const v4f*)wsm;

    for (int cs = 0; cs < cnt; cs += 4) {
        const float tb = (float)(s0 + cs);
        const v2f zv0 = {fmaf(stepz, tb,        nearv), fmaf(stepz, tb + 1.0f, nearv)};
        const v2f zv1 = {fmaf(stepz, tb + 2.0f, nearv), fmaf(stepz, tb + 3.0f, nearv)};
        const v2f X0 = clamp11(pkfma(dxp, zv0, oxp));
        const v2f Y0 = clamp11(pkfma(dyp, zv0, oyp));
        const v2f Z0 = clamp11(pkfma(dzp, zv0, ozp));
        const v2f X1 = clamp11(pkfma(dxp, zv1, oxp));
        const v2f Y1 = clamp11(pkfma(dyp, zv1, oyp));
        const v2f Z1 = clamp11(pkfma(dzp, zv1, ozp));

        v2f sA0v = {0,0}, sD0v = {0,0}, c0A0 = {0,0}, c1A0 = {0,0}, c2A0 = {0,0},
            c0D0 = {0,0}, c1D0 = {0,0}, c2D0 = {0,0};
        v2f sA1v = {0,0}, sD1v = {0,0}, c0A1 = {0,0}, c1A1 = {0,0}, c2A1 = {0,0},
            c0D1 = {0,0}, c1D1 = {0,0}, c2D1 = {0,0};

#pragma unroll 4
        for (int j = 0; j < 32; ++j) {
            // uniform-index loads -> s_load (SGPRs); pairs are even-aligned (w,w)
            const v4f q0 = wv[j*8 + 0];
            const v4f q1 = wv[j*8 + 1];
            const v4f q2 = wv[j*8 + 2];
            const v4f q3 = wv[j*8 + 3];
            const v4f q4 = wv[j*8 + 4];
            const v4f q5 = wv[j*8 + 5];
            const v4f q6 = wv[j*8 + 6];
            const v4f q7 = wv[j*8 + 7];
            const v2f dcp = dc2[rayL*33 + j];

            const v2f w1x = SHV(q0, 0, 1), w1y = SHV(q0, 2, 3);
            const v2f w1z = SHV(q1, 0, 1), b1p = SHV(q1, 2, 3);
            const v2f wsa = SHV(q2, 0, 1), wsd = SHV(q2, 2, 3);
            const v2f wcx = SHV(q3, 0, 1), wcy = SHV(q3, 2, 3);
            const v2f wcz = SHV(q4, 0, 1), wa0 = SHV(q4, 2, 3);
            const v2f wa1 = SHV(q5, 0, 1), wa2 = SHV(q5, 2, 3);
            const v2f wd0 = SHV(q6, 0, 1), wd1 = SHV(q6, 2, 3);
            const v2f wd2 = SHV(q7, 0, 1);

            v2f h0 = pkfma(X0, w1x, pkfma(Y0, w1y, pkfma(Z0, w1z, b1p)));
            v2f h1 = pkfma(X1, w1x, pkfma(Y1, w1y, pkfma(Z1, w1z, b1p)));
            h0 = relu2(h0); h1 = relu2(h1);
            sA0v = pkfma(h0, wsa, sA0v);  sD0v = pkfma(h0, wsd, sD0v);
            sA1v = pkfma(h1, wsa, sA1v);  sD1v = pkfma(h1, wsd, sD1v);

            v2f g0 = pkfma(X0, wcx, pkfma(Y0, wcy, pkfma(Z0, wcz, dcp)));
            v2f g1 = pkfma(X1, wcx, pkfma(Y1, wcy, pkfma(Z1, wcz, dcp)));
            g0 = relu2(g0); g1 = relu2(g1);
            c0A0 = pkfma(g0, wa0, c0A0);  c1A0 = pkfma(g0, wa1, c1A0);  c2A0 = pkfma(g0, wa2, c2A0);
            c0D0 = pkfma(g0, wd0, c0D0);  c1D0 = pkfma(g0, wd1, c1D0);  c2D0 = pkfma(g0, wd2, c2D0);
            c0A1 = pkfma(g1, wa0, c0A1);  c1A1 = pkfma(g1, wa1, c1A1);  c2A1 = pkfma(g1, wa2, c2A1);
            c0D1 = pkfma(g1, wd0, c0D1);  c1D1 = pkfma(g1, wd1, c1D1);  c2D1 = pkfma(g1, wd2, c2D1);
        }

#define COMPOSITE(I, SA, SD, R0A, R1A, R2A, R0D, R1D, R2D)                         \
        do {                                                                        \
            const int li = cs + (I);                                                \
            if (li < cnt) {                                                         \
                const int t = s0 + li;                                              \
                const float sigA = softplus_f(SA);                                  \
                const float sigD = softplus_f(SD);                                  \
                const float delta = (t < T - 1) ? stepz : last_dt;                  \
                const float z01 = fminf(fmaxf((float)t * inv_tm1, 0.0f), 1.0f);     \
                const float aA = 1.0f - __expf(-delta * sigA);                      \
                const float wA = aA * TAx;                                          \
                TAx = TAx * (1.0f - aA + 1e-15f);                                   \
                iA0 = fmaf(wA, sigmoid_f(R0A), iA0);                                \
                iA1 = fmaf(wA, sigmoid_f(R1A), iA1);                                \
                iA2 = fmaf(wA, sigmoid_f(R2A), iA2);                                \
                dAc = fmaf(wA, z01, dAc);                                           \
                wsA += wA;                                                          \
                const float aD = 1.0f - __expf(-delta * sigD);                      \
                const float wD = aD * TDx;                                          \
                TDx = TDx * (1.0f - aD + 1e-15f);                                   \
                iD0 = fmaf(wD, sigmoid_f(R0D), iD0);                                \
                iD1 = fmaf(wD, sigmoid_f(R1D), iD1);                                \
                iD2 = fmaf(wD, sigmoid_f(R2D), iD2);                                \
                dDc = fmaf(wD, z01, dDc);                                           \
                wsD += wD;                                                          \
            }                                                                       \
        } while (0)

        COMPOSITE(0, sA0v.x, sD0v.x, c0A0.x, c1A0.x, c2A0.x, c0D0.x, c1D0.x, c2D0.x);
        COMPOSITE(1, sA0v.y, sD0v.y, c0A0.y, c1A0.y, c2A0.y, c0D0.y, c1D0.y, c2D0.y);
        COMPOSITE(2, sA1v.x, sD1v.x, c0A1.x, c1A1.x, c2A1.x, c0D1.x, c1D1.x, c2D1.x);
        COMPOSITE(3, sA1v.y, sD1v.y, c0A1.y, c1A1.y, c2A1.y, c0D1.y, c1D1.y, c2D1.y);
#undef COMPOSITE
    }

    // combine 16 segments: exclusive prefix product of transmittance (log-scan),
    // scale each segment's contributions, butterfly-sum over the 16 lanes.
    const int lane16 = seg;
    float scanA = TAx, scanD = TDx;
#pragma unroll
    for (int off = 1; off < 16; off <<= 1) {
        const float tA_ = __shfl_up(scanA, off, 16);
        const float tD_ = __shfl_up(scanD, off, 16);
        if (lane16 >= off) { scanA *= tA_; scanD *= tD_; }
    }
    float exA = __shfl_up(scanA, 1, 16);
    float exD = __shfl_up(scanD, 1, 16);
    if (lane16 == 0) { exA = 1.0f; exD = 1.0f; }

    iA0 *= exA; iA1 *= exA; iA2 *= exA; dAc *= exA; wsA *= exA;
    iD0 *= exD; iD1 *= exD; iD2 *= exD; dDc *= exD; wsD *= exD;

#pragma unroll
    for (int mask = 1; mask < 16; mask <<= 1) {
        iA0 += __shfl_xor(iA0, mask, 16);
        iA1 += __shfl_xor(iA1, mask, 16);
        iA2 += __shfl_xor(iA2, mask, 16);
        dAc += __shfl_xor(dAc, mask, 16);
        wsA += __shfl_xor(wsA, mask, 16);
        iD0 += __shfl_xor(iD0, mask, 16);
        iD1 += __shfl_xor(iD1, mask, 16);
        iD2 += __shfl_xor(iD2, mask, 16);
        dDc += __shfl_xor(dDc, mask, 16);
        wsD += __shfl_xor(wsD, mask, 16);
    }

    if (seg == 0) {
        const float bgA = 1.0f - wsA;
        const float bgD = 1.0f - wsD;
        float* o = out + (size_t)ray * 9;
        o[0] = iA0 + bgA;
        o[1] = iA1 + bgA;
        o[2] = iA2 + bgA;
        o[3] = dAc;
        o[4] = wsA;
        o[5] = iD0 + bgD;
        o[6] = iD1 + bgD;
        o[7] = iD2 + bgD;
        o[8] = dDc;
    }
}

extern "C" void kernel_launch(void* const* d_in, const int* in_sizes, int n_in,
                              void* d_out, int out_size, void* d_ws, size_t ws_size,
                              hipStream_t stream) {
    const float* rays_o = (const float*)d_in[0];
    const float* rays_d = (const float*)d_in[1];
    const float* W1     = (const float*)d_in[2];
    const float* b1     = (const float*)d_in[3];
    const float* Wsig   = (const float*)d_in[4];
    const float* Wsig_d = (const float*)d_in[5];
    const float* Wc1    = (const float*)d_in[6];
    const float* bc1    = (const float*)d_in[7];
    const float* Wc2    = (const float*)d_in[8];
    const float* Wc2_d  = (const float*)d_in[9];
    const int* num_steps = (const int*)d_in[10];

    const int N = in_sizes[0] / 3;
    float* out = (float*)d_out;
    float* ws  = (float*)d_ws;   // needs 4 KB

    hipLaunchKernelGGL(nerf_prep_kernel, dim3(1), dim3(256), 0, stream,
                       W1, b1, Wsig, Wsig_d, Wc1, Wc2, Wc2_d, ws);

    const int blocks = (N + 15) / 16;   // 16 rays per 256-thread block
    hipLaunchKernelGGL(nerf_render_kernel, dim3(blocks), dim3(256), 0, stream,
                       rays_o, rays_d, Wc1, bc1, ws, num_steps, out, N);
}